// Round 14
// baseline (228.366 us; speedup 1.0000x reference)
//
#include <hip/hip_runtime.h>

#define FIN 100
#define FHID 100
#define FEMB 64
#define NCLS 40

#define BSH 6                 // 64 nodes per bucket
#define NSEG 8                // segments per bucket == number of XCDs (segment = XCC_ID)
#define SEGCAP 224            // >= E/NBK/NSEG (=128) + 8.5 sigma
#define CSTR 16               // cursor stride in ints: 1 cursor per 64B line

typedef __attribute__((ext_vector_type(8))) short short8;   // 8 bf16 (4 VGPRs) — MFMA A/B frag
typedef __attribute__((ext_vector_type(4))) float f32x4;    // MFMA C/D frag

// ---------- bf16 helpers (RNE) ----------
__device__ inline unsigned short f2bf(float f) {
    unsigned u = __float_as_uint(f);
    u += 0x7FFFu + ((u >> 16) & 1u);
    return (unsigned short)(u >> 16);
}
__device__ inline float bf2f(unsigned short s) {
    return __uint_as_float((unsigned)s << 16);
}
__device__ inline float4 bf4(ushort4 u) {
    return make_float4(bf2f(u.x), bf2f(u.y), bf2f(u.z), bf2f(u.w));
}

// XCD id (0..7 on MI355X) — learn_hip m09
__device__ inline unsigned xcc_id() {
    unsigned x;
    asm("s_getreg_b32 %0, hwreg(HW_REG_XCC_ID)" : "=s"(x));
    return x & (NSEG - 1);
}

// ============ bucket sort: histogram + atomic base reservation + place ============
__global__ __launch_bounds__(256) void k_bucket_sort(const int* __restrict__ arena,
                                                     const int* __restrict__ cur,
                                                     int* __restrict__ gcounter,
                                                     int* __restrict__ rowptr,
                                                     int* __restrict__ rowend,
                                                     float* __restrict__ dinv,
                                                     int* __restrict__ src_sorted, int n) {
    const int b = blockIdx.x;
    __shared__ int cnt[64], off[64];
    __shared__ int base_sh;
    if (threadIdx.x < 64) cnt[threadIdx.x] = 0;
    __syncthreads();
    for (int s = 0; s < NSEG; ++s) {
        int len = cur[(b * NSEG + s) * CSTR];
        if (len > SEGCAP) len = SEGCAP;
        const int* seg = arena + (size_t)(b * NSEG + s) * SEGCAP;
        for (int idx = threadIdx.x; idx < len; idx += 256)
            atomicAdd(&cnt[seg[idx] & 63], 1);
    }
    __syncthreads();
    if (threadIdx.x == 0) {
        int run = 0;
        for (int j = 0; j < 64; ++j) { off[j] = run; run += cnt[j]; }
        base_sh = atomicAdd(gcounter, run);
    }
    __syncthreads();
    const int base = base_sh;
    if (threadIdx.x < 64) {
        int node = (b << BSH) + threadIdx.x;
        if (node < n) {
            int r0 = base + off[threadIdx.x];
            rowptr[node] = r0;
            rowend[node] = r0 + cnt[threadIdx.x];
            dinv[node] = rsqrtf((float)cnt[threadIdx.x] + 1.0f);  // +1 self-loop
        }
    }
    __syncthreads();
    for (int s = 0; s < NSEG; ++s) {
        int len = cur[(b * NSEG + s) * CSTR];
        if (len > SEGCAP) len = SEGCAP;
        const int* seg = arena + (size_t)(b * NSEG + s) * SEGCAP;
        for (int idx = threadIdx.x; idx < len; idx += 256) {
            int v = seg[idx];
            int lpos = atomicAdd(&off[v & 63], 1);
            src_sorted[base + lpos] = v >> BSH;
        }
    }
}

// ====== MFMA bf16 GEMM: 128-row block, col-tiles processed in passes of NTY ======
// 4 waves in 2x2 per pass. Optional fused edge-scatter prologue (segment = XCC_ID:
// all writers of an arena stream live on one XCD -> lines pack in that XCD's L2,
// single writeback; cross-XCD interleaving cost ~32MB extra WRITE in R13).
// mfma_f32_16x16x32_bf16 layouts per learn_hip m89/m91.
template <int KIN, int KOUT, int NTY, bool A_BF16, bool BIAS, bool OUT_BF16, bool SCATTER>
__global__ __launch_bounds__(256) void k_gemm_mfma(const void* __restrict__ A,
                                                   const float* __restrict__ W,
                                                   const float* __restrict__ bias,
                                                   void* __restrict__ C, int n,
                                                   const int* __restrict__ src,
                                                   const int* __restrict__ dst,
                                                   int* __restrict__ cur,
                                                   int* __restrict__ arena, int E) {
    constexpr int KP    = ((KIN + 31) / 32) * 32;
    constexpr int NTALL = (KOUT + 15) / 16;       // total col tiles
    constexpr int NTC   = NTY * 16;               // cols staged per pass
    constexpr int APAD  = KP + 8;
    constexpr int NKC   = KP / 32;
    constexpr int TQ    = (NTY + 1) / 2;
    constexpr int KQ4   = KIN / 4;

    __shared__ unsigned short Abf[128 * APAD];
    __shared__ unsigned short Wt[NTC * APAD];

    const int row0 = blockIdx.x * 128;
    const int tid = threadIdx.x;

    // ---- optional scatter prologue ----
    if constexpr (SCATTER) {
        const unsigned myseg = xcc_id();
        const int stride = gridDim.x * 256;
        for (int e = blockIdx.x * 256 + tid; e < E; e += stride) {
            int d = dst[e];
            int b = d >> BSH;
            int slot = b * NSEG + myseg;
            int p = atomicAdd(&cur[slot * CSTR], 1);
            if (p < SEGCAP) arena[slot * SEGCAP + p] = (src[e] << BSH) | (d & 63);
        }
    }

    // ---- stage A tile as bf16 (once) ----
    if constexpr (A_BF16) {
        const ushort4* A4 = (const ushort4*)A;
        for (int idx = tid; idx < 128 * KQ4; idx += 256) {
            int r = idx / KQ4;
            int kq = idx - r * KQ4;
            ushort4 v = make_ushort4(0, 0, 0, 0);
            if (row0 + r < n) v = A4[(size_t)(row0 + r) * KQ4 + kq];
            *(ushort4*)&Abf[r * APAD + kq * 4] = v;
        }
    } else {
        const float* Af = (const float*)A;
        for (int idx = tid; idx < 128 * KQ4; idx += 256) {
            int r = idx / KQ4;
            int kq = idx - r * KQ4;
            float4 v = make_float4(0.f, 0.f, 0.f, 0.f);
            if (row0 + r < n) v = ((const float4*)(Af + (size_t)(row0 + r) * KIN))[kq];
            ushort4 o;
            o.x = f2bf(v.x); o.y = f2bf(v.y); o.z = f2bf(v.z); o.w = f2bf(v.w);
            *(ushort4*)&Abf[r * APAD + kq * 4] = o;
        }
    }
    if (KP > KIN) {
        constexpr int PADW = (KP > KIN) ? (KP - KIN) : 1;
        for (int idx = tid; idx < 128 * PADW; idx += 256) {
            int r = idx / PADW;
            Abf[r * APAD + KIN + (idx - r * PADW)] = 0;
        }
    }

    const int lane = tid & 63;
    const int w    = tid >> 6;
    const int m0   = (w >> 1) * 64;
    const int t0   = (w & 1) * TQ;
    const int lm   = lane & 15;
    const int quad = lane >> 4;

    // ---- pass loop over column-tile groups ----
    for (int tb = 0; tb < NTALL; tb += NTY) {
        const int ntloc = (NTALL - tb < NTY) ? (NTALL - tb) : NTY;

        for (int idx = tid; idx < KIN * NTC; idx += 256) {
            int k = idx / NTC;
            int c = idx - k * NTC;
            int gc = tb * 16 + c;
            float v = (gc < KOUT) ? W[(size_t)k * KOUT + gc] : 0.f;
            Wt[c * APAD + k] = f2bf(v);
        }
        if (KP > KIN) {
            constexpr int PADW = (KP > KIN) ? (KP - KIN) : 1;
            for (int idx = tid; idx < NTC * PADW; idx += 256) {
                int c = idx / PADW;
                Wt[c * APAD + KIN + (idx - c * PADW)] = 0;
            }
        }
        __syncthreads();

        const int tcnt = (ntloc - t0 < TQ) ? (ntloc - t0) : TQ;  // may be <= 0

        f32x4 acc[4][TQ];
        #pragma unroll
        for (int i = 0; i < 4; ++i)
            #pragma unroll
            for (int t = 0; t < TQ; ++t)
                acc[i][t] = (f32x4)(0.f);

        for (int kt = 0; kt < NKC; ++kt) {
            short8 a[4], b[TQ];
            #pragma unroll
            for (int i = 0; i < 4; ++i)
                a[i] = *(const short8*)&Abf[(m0 + i * 16 + lm) * APAD + kt * 32 + quad * 8];
            #pragma unroll
            for (int t = 0; t < TQ; ++t)
                if (t < tcnt)
                    b[t] = *(const short8*)&Wt[((t0 + t) * 16 + lm) * APAD + kt * 32 + quad * 8];
            #pragma unroll
            for (int i = 0; i < 4; ++i)
                #pragma unroll
                for (int t = 0; t < TQ; ++t)
                    if (t < tcnt)
                        acc[i][t] = __builtin_amdgcn_mfma_f32_16x16x32_bf16(a[i], b[t], acc[i][t], 0, 0, 0);
        }

        #pragma unroll
        for (int t = 0; t < TQ; ++t) {
            if (t >= tcnt) continue;
            int col = (tb + t0 + t) * 16 + lm;
            if (col >= KOUT) continue;
            float bv = BIAS ? bias[col] : 0.f;
            #pragma unroll
            for (int i = 0; i < 4; ++i) {
                #pragma unroll
                for (int rg = 0; rg < 4; ++rg) {
                    int row = row0 + m0 + i * 16 + quad * 4 + rg;
                    if (row < n) {
                        float v = acc[i][t][rg] + bv;
                        if (OUT_BF16)
                            ((unsigned short*)C)[(size_t)row * KOUT + col] = f2bf(v);
                        else
                            ((float*)C)[(size_t)row * KOUT + col] = v;
                    }
                }
            }
        }
        __syncthreads();   // protect Wt before next pass restage
    }
}

// ===== CSR aggregation over bf16 h, fused bias + ReLU, bf16 output =====
template <int F>
__global__ __launch_bounds__(256) void k_agg_bf(const unsigned short* __restrict__ h,
                                                const int* __restrict__ rowptr,
                                                const int* __restrict__ rowend,
                                                const int* __restrict__ src_sorted,
                                                const float* __restrict__ dinv,
                                                const float* __restrict__ bias,
                                                unsigned short* __restrict__ out, int n) {
    const int G = F / 4;
    int gid = blockIdx.x * blockDim.x + threadIdx.x;
    if (gid >= n * G) return;
    int i = gid / G;
    int cq = gid % G;
    const ushort4* h4 = (const ushort4*)h;

    float4 acc = make_float4(0.f, 0.f, 0.f, 0.f);
    int e = rowptr[i];
    const int end = rowend[i];
    for (; e + 3 < end; e += 4) {
        int s0 = src_sorted[e];
        int s1 = src_sorted[e + 1];
        int s2 = src_sorted[e + 2];
        int s3 = src_sorted[e + 3];
        ushort4 u0 = h4[(size_t)s0 * G + cq];
        ushort4 u1 = h4[(size_t)s1 * G + cq];
        ushort4 u2 = h4[(size_t)s2 * G + cq];
        ushort4 u3 = h4[(size_t)s3 * G + cq];
        float n0 = dinv[s0], n1 = dinv[s1], n2 = dinv[s2], n3 = dinv[s3];
        float4 v0 = bf4(u0), v1 = bf4(u1), v2 = bf4(u2), v3 = bf4(u3);
        acc.x = fmaf(v0.x, n0, acc.x); acc.y = fmaf(v0.y, n0, acc.y);
        acc.z = fmaf(v0.z, n0, acc.z); acc.w = fmaf(v0.w, n0, acc.w);
        acc.x = fmaf(v1.x, n1, acc.x); acc.y = fmaf(v1.y, n1, acc.y);
        acc.z = fmaf(v1.z, n1, acc.z); acc.w = fmaf(v1.w, n1, acc.w);
        acc.x = fmaf(v2.x, n2, acc.x); acc.y = fmaf(v2.y, n2, acc.y);
        acc.z = fmaf(v2.z, n2, acc.z); acc.w = fmaf(v2.w, n2, acc.w);
        acc.x = fmaf(v3.x, n3, acc.x); acc.y = fmaf(v3.y, n3, acc.y);
        acc.z = fmaf(v3.z, n3, acc.z); acc.w = fmaf(v3.w, n3, acc.w);
    }
    for (; e < end; ++e) {
        int s0 = src_sorted[e];
        float n0 = dinv[s0];
        float4 v0 = bf4(h4[(size_t)s0 * G + cq]);
        acc.x = fmaf(v0.x, n0, acc.x); acc.y = fmaf(v0.y, n0, acc.y);
        acc.z = fmaf(v0.z, n0, acc.z); acc.w = fmaf(v0.w, n0, acc.w);
    }

    float d = dinv[i];
    float4 hv = bf4(h4[(size_t)i * G + cq]);
    float4 bv = *(const float4*)&bias[cq * 4];
    ushort4 st;
    st.x = f2bf(fmaxf(fmaf(d, fmaf(d, hv.x, acc.x), bv.x), 0.f));
    st.y = f2bf(fmaxf(fmaf(d, fmaf(d, hv.y, acc.y), bv.y), 0.f));
    st.z = f2bf(fmaxf(fmaf(d, fmaf(d, hv.z, acc.z), bv.z), 0.f));
    st.w = f2bf(fmaxf(fmaf(d, fmaf(d, hv.w, acc.w), bv.w), 0.f));
    ((ushort4*)out)[(size_t)i * G + cq] = st;
}

extern "C" void kernel_launch(void* const* d_in, const int* in_sizes, int n_in,
                              void* d_out, int out_size, void* d_ws, size_t ws_size,
                              hipStream_t stream) {
    const float* x  = (const float*)d_in[0];
    const int*   ei = (const int*)d_in[1];
    const float* W1 = (const float*)d_in[2];
    const float* b1 = (const float*)d_in[3];
    const float* W2 = (const float*)d_in[4];
    const float* b2 = (const float*)d_in[5];
    const float* Wc = (const float*)d_in[6];
    const float* bc = (const float*)d_in[7];
    float* out = (float*)d_out;

    const int N = in_sizes[0] / FIN;
    const int E = in_sizes[1] / 2;
    const int* src = ei;
    const int* dst = ei + E;
    const int NBK = (N + 63) >> BSH;  // 782 for N=50k

    auto align = [](size_t v) { return (v + 255) & ~(size_t)255; };
    char* ws = (char*)d_ws;
    const size_t cur_bytes = align((size_t)NBK * NSEG * CSTR * 4 + 256);
    int*   cur        = (int*)ws;   ws += cur_bytes;
    int*   gcounter   = cur + (size_t)NBK * NSEG * CSTR;   // inside the memset region
    int*   arena      = (int*)ws;   ws += align((size_t)NBK * NSEG * SEGCAP * 4);
    int*   rowptr     = (int*)ws;   ws += align((size_t)N * 4);
    int*   rowend     = (int*)ws;   ws += align((size_t)N * 4);
    int*   src_sorted = (int*)ws;   ws += align((size_t)E * 4);
    float* dinv       = (float*)ws; ws += align((size_t)N * 4);
    unsigned short* h1  = (unsigned short*)ws; ws += align((size_t)N * FHID * 2);
    unsigned short* a1r = (unsigned short*)ws; ws += align((size_t)N * FHID * 2);
    unsigned short* h2  = (unsigned short*)ws; ws += align((size_t)N * FEMB * 2);
    unsigned short* a2r = (unsigned short*)ws; ws += align((size_t)N * FEMB * 2);

    const int B = 256;
    const int nmb = (N + 127) / 128;  // 391 MFMA row-tiles

    // 1) zero cursors + gcounter
    hipMemsetAsync(cur, 0, cur_bytes, stream);

    // 2) layer-1 GEMM (two Wt passes, 52KB LDS) with fused edge scatter (XCD-local segments)
    k_gemm_mfma<FIN, FHID, 4, false, false, true, true><<<nmb, B, 0, stream>>>(
        x, W1, nullptr, h1, N, src, dst, cur, arena, E);

    // 3) bucket sort -> rowptr/rowend/dinv/src_sorted
    k_bucket_sort<<<NBK, B, 0, stream>>>(arena, cur, gcounter, rowptr, rowend, dinv, src_sorted, N);

    // 4) a1r(bf16) = relu(agg(h1) + b1)
    k_agg_bf<FHID><<<((size_t)N * (FHID / 4) + B - 1) / B, B, 0, stream>>>(
        h1, rowptr, rowend, src_sorted, dinv, b1, a1r, N);

    // 5) h2(bf16) = a1r @ W2  (single pass: NT=4)
    k_gemm_mfma<FHID, FEMB, 4, true, false, true, false><<<nmb, B, 0, stream>>>(
        a1r, W2, nullptr, h2, N, nullptr, nullptr, nullptr, nullptr, 0);

    // 6) a2r(bf16) = relu(agg(h2) + b2)
    k_agg_bf<FEMB><<<((size_t)N * (FEMB / 4) + B - 1) / B, B, 0, stream>>>(
        h2, rowptr, rowend, src_sorted, dinv, b2, a2r, N);

    // 7) out(fp32) = a2r @ Wc + bc  (single pass: NT=3; 27.6KB LDS)
    k_gemm_mfma<FEMB, NCLS, 4, true, true, false, false><<<nmb, B, 0, stream>>>(
        a2r, Wc, bc, out, N, nullptr, nullptr, nullptr, nullptr, 0);
}

// Round 15
// 210.640 us; speedup vs baseline: 1.0842x; 1.0842x over previous
//
#include <hip/hip_runtime.h>

#define FIN 100
#define FHID 100
#define FEMB 64
#define NCLS 40

#define SBSH 8                // 256 nodes per super-bucket
#define CAPB 24               // LDS bin capacity per block (mean 10.4; overflow -> global spill path)
#define SBCAP 4608            // per-super-bucket arena cap: mean 4096 + 8 sigma
#define CSTR 16               // cursor stride in ints: 1 cursor per 64B line
#define EPB 2048              // edges per scatter block

typedef __attribute__((ext_vector_type(8))) short short8;   // 8 bf16 (4 VGPRs) — MFMA A/B frag
typedef __attribute__((ext_vector_type(4))) float f32x4;    // MFMA C/D frag

// ---------- bf16 helpers (RNE) ----------
__device__ inline unsigned short f2bf(float f) {
    unsigned u = __float_as_uint(f);
    u += 0x7FFFu + ((u >> 16) & 1u);
    return (unsigned short)(u >> 16);
}
__device__ inline float bf2f(unsigned short s) {
    return __uint_as_float((unsigned)s << 16);
}
__device__ inline float4 bf4(ushort4 u) {
    return make_float4(bf2f(u.x), bf2f(u.y), bf2f(u.z), bf2f(u.w));
}

// ============ LDS-binned edge scatter: coalesced burst appends to per-super-bucket arenas ============
// rec = (src << 8) | (dst & 255); sb = dst >> 8. One cursor atomic per (block, bin) instead of per edge.
__global__ __launch_bounds__(256) void k_scatter_bin(const int* __restrict__ src,
                                                     const int* __restrict__ dst,
                                                     int* __restrict__ gcur,
                                                     int* __restrict__ arena,
                                                     int E, int nsb) {
    __shared__ int bins[256 * CAPB];
    __shared__ int bcnt[256];
    __shared__ int pbase[256];
    const int tid = threadIdx.x;
    bcnt[tid] = 0;
    __syncthreads();

    const int e0 = blockIdx.x * EPB;
    #pragma unroll
    for (int k = 0; k < EPB / 256; ++k) {
        int e = e0 + k * 256 + tid;
        if (e < E) {
            int d = dst[e];
            int sb = d >> SBSH;
            int rec = (src[e] << SBSH) | (d & 255);
            int c = atomicAdd(&bcnt[sb], 1);
            if (c < CAPB) {
                bins[sb * CAPB + c] = rec;
            } else {  // rare overflow: direct global append (correct, slow path)
                int p = atomicAdd(&gcur[sb * CSTR], 1);
                if (p < SBCAP) arena[(size_t)sb * SBCAP + p] = rec;
            }
        }
    }
    __syncthreads();

    // step 1: one cursor atomic per non-empty bin (parallel across 196 threads)
    if (tid < nsb) {
        int c = bcnt[tid];
        if (c > CAPB) c = CAPB;
        pbase[tid] = (c > 0) ? atomicAdd(&gcur[tid * CSTR], c) : 0;
    }
    __syncthreads();

    // step 2: burst-copy bins to arena (lane l writes entry l: contiguous -> coalesced lines)
    const int wv = tid >> 6, lane = tid & 63;
    for (int sb = wv; sb < nsb; sb += 4) {
        int c = bcnt[sb];
        if (c > CAPB) c = CAPB;
        int p = pbase[sb];
        if (lane < c && p + lane < SBCAP)
            arena[(size_t)sb * SBCAP + p + lane] = bins[sb * CAPB + lane];
    }
}

// ============ per-super-bucket sort: 256-node histogram + atomic base + place ============
__global__ __launch_bounds__(256) void k_bucket_sort(const int* __restrict__ arena,
                                                     const int* __restrict__ gcur,
                                                     int* __restrict__ gcounter,
                                                     int* __restrict__ rowptr,
                                                     int* __restrict__ rowend,
                                                     float* __restrict__ dinv,
                                                     int* __restrict__ src_sorted, int n) {
    const int sb = blockIdx.x;
    const int tid = threadIdx.x;
    __shared__ int cnt[256], off[256], tmp[256];
    __shared__ int base_sh;
    cnt[tid] = 0;
    __syncthreads();

    int len = gcur[sb * CSTR];
    if (len > SBCAP) len = SBCAP;
    const int* seg = arena + (size_t)sb * SBCAP;
    for (int i = tid; i < len; i += 256)
        atomicAdd(&cnt[seg[i] & 255], 1);
    __syncthreads();

    // exclusive scan of cnt (Hillis-Steele, 256 threads == 256 counters)
    const int v = cnt[tid];
    tmp[tid] = v;
    __syncthreads();
    for (int o = 1; o < 256; o <<= 1) {
        int t = (tid >= o) ? tmp[tid - o] : 0;
        __syncthreads();
        tmp[tid] += t;
        __syncthreads();
    }
    off[tid] = tmp[tid] - v;  // exclusive
    if (tid == 255) base_sh = atomicAdd(gcounter, tmp[255]);
    __syncthreads();

    const int base = base_sh;
    int node = (sb << SBSH) + tid;
    if (node < n) {
        int r0 = base + off[tid];
        rowptr[node] = r0;
        rowend[node] = r0 + v;
        dinv[node] = rsqrtf((float)v + 1.0f);  // +1 self-loop
    }
    __syncthreads();

    // place (off doubles as cursor)
    for (int i = tid; i < len; i += 256) {
        int rec = seg[i];
        int lpos = atomicAdd(&off[rec & 255], 1);
        src_sorted[base + lpos] = rec >> SBSH;
    }
}

// ====== MFMA bf16 GEMM: 128-row block, col-tiles processed in passes of NTY ======
// 4 waves in 2x2 per pass. mfma_f32_16x16x32_bf16 layouts per learn_hip m89/m91.
template <int KIN, int KOUT, int NTY, bool A_BF16, bool BIAS, bool OUT_BF16>
__global__ __launch_bounds__(256) void k_gemm_mfma(const void* __restrict__ A,
                                                   const float* __restrict__ W,
                                                   const float* __restrict__ bias,
                                                   void* __restrict__ C, int n) {
    constexpr int KP    = ((KIN + 31) / 32) * 32;
    constexpr int NTALL = (KOUT + 15) / 16;       // total col tiles
    constexpr int NTC   = NTY * 16;               // cols staged per pass
    constexpr int APAD  = KP + 8;
    constexpr int NKC   = KP / 32;
    constexpr int TQ    = (NTY + 1) / 2;
    constexpr int KQ4   = KIN / 4;

    __shared__ unsigned short Abf[128 * APAD];
    __shared__ unsigned short Wt[NTC * APAD];

    const int row0 = blockIdx.x * 128;
    const int tid = threadIdx.x;

    // ---- stage A tile as bf16 (once) ----
    if constexpr (A_BF16) {
        const ushort4* A4 = (const ushort4*)A;
        for (int idx = tid; idx < 128 * KQ4; idx += 256) {
            int r = idx / KQ4;
            int kq = idx - r * KQ4;
            ushort4 v = make_ushort4(0, 0, 0, 0);
            if (row0 + r < n) v = A4[(size_t)(row0 + r) * KQ4 + kq];
            *(ushort4*)&Abf[r * APAD + kq * 4] = v;
        }
    } else {
        const float* Af = (const float*)A;
        for (int idx = tid; idx < 128 * KQ4; idx += 256) {
            int r = idx / KQ4;
            int kq = idx - r * KQ4;
            float4 v = make_float4(0.f, 0.f, 0.f, 0.f);
            if (row0 + r < n) v = ((const float4*)(Af + (size_t)(row0 + r) * KIN))[kq];
            ushort4 o;
            o.x = f2bf(v.x); o.y = f2bf(v.y); o.z = f2bf(v.z); o.w = f2bf(v.w);
            *(ushort4*)&Abf[r * APAD + kq * 4] = o;
        }
    }
    if (KP > KIN) {
        constexpr int PADW = (KP > KIN) ? (KP - KIN) : 1;
        for (int idx = tid; idx < 128 * PADW; idx += 256) {
            int r = idx / PADW;
            Abf[r * APAD + KIN + (idx - r * PADW)] = 0;
        }
    }

    const int lane = tid & 63;
    const int w    = tid >> 6;
    const int m0   = (w >> 1) * 64;
    const int t0   = (w & 1) * TQ;
    const int lm   = lane & 15;
    const int quad = lane >> 4;

    // ---- pass loop over column-tile groups ----
    for (int tb = 0; tb < NTALL; tb += NTY) {
        const int ntloc = (NTALL - tb < NTY) ? (NTALL - tb) : NTY;

        for (int idx = tid; idx < KIN * NTC; idx += 256) {
            int k = idx / NTC;
            int c = idx - k * NTC;
            int gc = tb * 16 + c;
            float v = (gc < KOUT) ? W[(size_t)k * KOUT + gc] : 0.f;
            Wt[c * APAD + k] = f2bf(v);
        }
        if (KP > KIN) {
            constexpr int PADW = (KP > KIN) ? (KP - KIN) : 1;
            for (int idx = tid; idx < NTC * PADW; idx += 256) {
                int c = idx / PADW;
                Wt[c * APAD + KIN + (idx - c * PADW)] = 0;
            }
        }
        __syncthreads();

        const int tcnt = (ntloc - t0 < TQ) ? (ntloc - t0) : TQ;  // may be <= 0

        f32x4 acc[4][TQ];
        #pragma unroll
        for (int i = 0; i < 4; ++i)
            #pragma unroll
            for (int t = 0; t < TQ; ++t)
                acc[i][t] = (f32x4)(0.f);

        for (int kt = 0; kt < NKC; ++kt) {
            short8 a[4], b[TQ];
            #pragma unroll
            for (int i = 0; i < 4; ++i)
                a[i] = *(const short8*)&Abf[(m0 + i * 16 + lm) * APAD + kt * 32 + quad * 8];
            #pragma unroll
            for (int t = 0; t < TQ; ++t)
                if (t < tcnt)
                    b[t] = *(const short8*)&Wt[((t0 + t) * 16 + lm) * APAD + kt * 32 + quad * 8];
            #pragma unroll
            for (int i = 0; i < 4; ++i)
                #pragma unroll
                for (int t = 0; t < TQ; ++t)
                    if (t < tcnt)
                        acc[i][t] = __builtin_amdgcn_mfma_f32_16x16x32_bf16(a[i], b[t], acc[i][t], 0, 0, 0);
        }

        #pragma unroll
        for (int t = 0; t < TQ; ++t) {
            if (t >= tcnt) continue;
            int col = (tb + t0 + t) * 16 + lm;
            if (col >= KOUT) continue;
            float bv = BIAS ? bias[col] : 0.f;
            #pragma unroll
            for (int i = 0; i < 4; ++i) {
                #pragma unroll
                for (int rg = 0; rg < 4; ++rg) {
                    int row = row0 + m0 + i * 16 + quad * 4 + rg;
                    if (row < n) {
                        float v = acc[i][t][rg] + bv;
                        if (OUT_BF16)
                            ((unsigned short*)C)[(size_t)row * KOUT + col] = f2bf(v);
                        else
                            ((float*)C)[(size_t)row * KOUT + col] = v;
                    }
                }
            }
        }
        __syncthreads();   // protect Wt before next pass restage
    }
}

// ===== CSR aggregation over bf16 h, fused bias + ReLU, bf16 output =====
template <int F>
__global__ __launch_bounds__(256) void k_agg_bf(const unsigned short* __restrict__ h,
                                                const int* __restrict__ rowptr,
                                                const int* __restrict__ rowend,
                                                const int* __restrict__ src_sorted,
                                                const float* __restrict__ dinv,
                                                const float* __restrict__ bias,
                                                unsigned short* __restrict__ out, int n) {
    const int G = F / 4;
    int gid = blockIdx.x * blockDim.x + threadIdx.x;
    if (gid >= n * G) return;
    int i = gid / G;
    int cq = gid % G;
    const ushort4* h4 = (const ushort4*)h;

    float4 acc = make_float4(0.f, 0.f, 0.f, 0.f);
    int e = rowptr[i];
    const int end = rowend[i];
    for (; e + 3 < end; e += 4) {
        int s0 = src_sorted[e];
        int s1 = src_sorted[e + 1];
        int s2 = src_sorted[e + 2];
        int s3 = src_sorted[e + 3];
        ushort4 u0 = h4[(size_t)s0 * G + cq];
        ushort4 u1 = h4[(size_t)s1 * G + cq];
        ushort4 u2 = h4[(size_t)s2 * G + cq];
        ushort4 u3 = h4[(size_t)s3 * G + cq];
        float n0 = dinv[s0], n1 = dinv[s1], n2 = dinv[s2], n3 = dinv[s3];
        float4 v0 = bf4(u0), v1 = bf4(u1), v2 = bf4(u2), v3 = bf4(u3);
        acc.x = fmaf(v0.x, n0, acc.x); acc.y = fmaf(v0.y, n0, acc.y);
        acc.z = fmaf(v0.z, n0, acc.z); acc.w = fmaf(v0.w, n0, acc.w);
        acc.x = fmaf(v1.x, n1, acc.x); acc.y = fmaf(v1.y, n1, acc.y);
        acc.z = fmaf(v1.z, n1, acc.z); acc.w = fmaf(v1.w, n1, acc.w);
        acc.x = fmaf(v2.x, n2, acc.x); acc.y = fmaf(v2.y, n2, acc.y);
        acc.z = fmaf(v2.z, n2, acc.z); acc.w = fmaf(v2.w, n2, acc.w);
        acc.x = fmaf(v3.x, n3, acc.x); acc.y = fmaf(v3.y, n3, acc.y);
        acc.z = fmaf(v3.z, n3, acc.z); acc.w = fmaf(v3.w, n3, acc.w);
    }
    for (; e < end; ++e) {
        int s0 = src_sorted[e];
        float n0 = dinv[s0];
        float4 v0 = bf4(h4[(size_t)s0 * G + cq]);
        acc.x = fmaf(v0.x, n0, acc.x); acc.y = fmaf(v0.y, n0, acc.y);
        acc.z = fmaf(v0.z, n0, acc.z); acc.w = fmaf(v0.w, n0, acc.w);
    }

    float d = dinv[i];
    float4 hv = bf4(h4[(size_t)i * G + cq]);
    float4 bv = *(const float4*)&bias[cq * 4];
    ushort4 st;
    st.x = f2bf(fmaxf(fmaf(d, fmaf(d, hv.x, acc.x), bv.x), 0.f));
    st.y = f2bf(fmaxf(fmaf(d, fmaf(d, hv.y, acc.y), bv.y), 0.f));
    st.z = f2bf(fmaxf(fmaf(d, fmaf(d, hv.z, acc.z), bv.z), 0.f));
    st.w = f2bf(fmaxf(fmaf(d, fmaf(d, hv.w, acc.w), bv.w), 0.f));
    ((ushort4*)out)[(size_t)i * G + cq] = st;
}

extern "C" void kernel_launch(void* const* d_in, const int* in_sizes, int n_in,
                              void* d_out, int out_size, void* d_ws, size_t ws_size,
                              hipStream_t stream) {
    const float* x  = (const float*)d_in[0];
    const int*   ei = (const int*)d_in[1];
    const float* W1 = (const float*)d_in[2];
    const float* b1 = (const float*)d_in[3];
    const float* W2 = (const float*)d_in[4];
    const float* b2 = (const float*)d_in[5];
    const float* Wc = (const float*)d_in[6];
    const float* bc = (const float*)d_in[7];
    float* out = (float*)d_out;

    const int N = in_sizes[0] / FIN;
    const int E = in_sizes[1] / 2;
    const int* src = ei;
    const int* dst = ei + E;
    const int NSB = (N + 255) >> SBSH;  // 196 for N=50k (k_scatter_bin requires <= 256)

    auto align = [](size_t v) { return (v + 255) & ~(size_t)255; };
    char* ws = (char*)d_ws;
    const size_t cur_bytes = align((size_t)256 * CSTR * 4 + 256);
    int*   gcur       = (int*)ws;   ws += cur_bytes;
    int*   gcounter   = gcur + 256 * CSTR;   // inside the memset region
    int*   arena      = (int*)ws;   ws += align((size_t)NSB * SBCAP * 4);
    int*   rowptr     = (int*)ws;   ws += align((size_t)N * 4);
    int*   rowend     = (int*)ws;   ws += align((size_t)N * 4);
    int*   src_sorted = (int*)ws;   ws += align((size_t)E * 4);
    float* dinv       = (float*)ws; ws += align((size_t)N * 4);
    unsigned short* h1  = (unsigned short*)ws; ws += align((size_t)N * FHID * 2);
    unsigned short* a1r = (unsigned short*)ws; ws += align((size_t)N * FHID * 2);
    unsigned short* h2  = (unsigned short*)ws; ws += align((size_t)N * FEMB * 2);
    unsigned short* a2r = (unsigned short*)ws; ws += align((size_t)N * FEMB * 2);

    const int B = 256;
    const int nmb = (N + 127) / 128;  // 391 MFMA row-tiles

    // 1) zero cursors + gcounter
    hipMemsetAsync(gcur, 0, cur_bytes, stream);

    // 2) LDS-binned edge scatter (coalesced burst appends)
    k_scatter_bin<<<(E + EPB - 1) / EPB, B, 0, stream>>>(src, dst, gcur, arena, E, NSB);

    // 3) per-super-bucket sort -> rowptr/rowend/dinv/src_sorted
    k_bucket_sort<<<NSB, B, 0, stream>>>(arena, gcur, gcounter, rowptr, rowend, dinv, src_sorted, N);

    // 4) h1(bf16) = x @ W1  (two Wt passes, 52KB LDS)
    k_gemm_mfma<FIN, FHID, 4, false, false, true><<<nmb, B, 0, stream>>>(x, W1, nullptr, h1, N);

    // 5) a1r(bf16) = relu(agg(h1) + b1)
    k_agg_bf<FHID><<<((size_t)N * (FHID / 4) + B - 1) / B, B, 0, stream>>>(
        h1, rowptr, rowend, src_sorted, dinv, b1, a1r, N);

    // 6) h2(bf16) = a1r @ W2
    k_gemm_mfma<FHID, FEMB, 4, true, false, true><<<nmb, B, 0, stream>>>(a1r, W2, nullptr, h2, N);

    // 7) a2r(bf16) = relu(agg(h2) + b2)
    k_agg_bf<FEMB><<<((size_t)N * (FEMB / 4) + B - 1) / B, B, 0, stream>>>(
        h2, rowptr, rowend, src_sorted, dinv, b2, a2r, N);

    // 8) out(fp32) = a2r @ Wc + bc
    k_gemm_mfma<FEMB, NCLS, 4, true, true, false><<<nmb, B, 0, stream>>>(a2r, Wc, bc, out, N);
}